// Round 4
// baseline (697.187 us; speedup 1.0000x reference)
//
#include <hip/hip_runtime.h>
#include <stdint.h>

// ---------------------------------------------------------------------------
// Ternary 3x3 conv block via i8 MFMA implicit GEMM, occupancy-tuned.
//
// Activations: NHWC i8 ternary {-1,0,+1}, padded [64][58][58][256], halo = 0
//   (halos zeroed by halo_zero_kernel; interiors fully written each launch).
// Weights pre-packed in MFMA B-fragment order:
//   Bpk[nfrag(16)][kstep(36)][lane(64)][16B], k = tap*256 + ci.
// mconv block: M=112 (2 out rows) x N=128 (co half, blockIdx.z) x K=2304.
//   4 waves: M-split {frags 0..3, frags 4..6} x N-split {co 0..63, 64..127}.
//   Ring-3 LDS (47.3 KB): tap-row r needs input rows {r0+r, r0+r+1} only.
//   C/D layout: col=lane&15, row=(lane>>4)*4+reg (verified R3, absmax 0).
// ---------------------------------------------------------------------------

#define NB 64
#define C  256
#define H  56
#define W  56
#define HP 58
#define PPIX 272                 // padded bytes per pixel in LDS (17*16)
#define SLOT (HP * PPIX)         // 15776 B per LDS row slot
#define OST 144                  // stage-1 out-transpose row stride (128+16)

typedef int v4i __attribute__((ext_vector_type(4)));

__global__ __launch_bounds__(256)
void pack_x_kernel(const float* __restrict__ x, int8_t* __restrict__ Aq) {
    const int h = blockIdx.x, n = blockIdx.y;
    const int w  = threadIdx.x & 63;   // 0..55 valid
    const int cg = threadIdx.x >> 6;   // 64-channel group
    if (w >= 56) return;
    const float* xp = x + (((size_t)n * C + cg * 64) * H + h) * W + w;
    uint32_t pk[16];
#pragma unroll
    for (int q = 0; q < 16; ++q) {
        uint32_t u = 0;
#pragma unroll
        for (int b = 0; b < 4; ++b) {
            float v = xp[(size_t)(q * 4 + b) * (H * W)];
            uint32_t t = (v < 0.0f) ? 0xFFu : ((v != 0.0f) ? 1u : 0u);
            u |= t << (8 * b);
        }
        pk[q] = u;
    }
    int8_t* dst = Aq + (((size_t)n * HP + h + 1) * HP + w + 1) * C + cg * 64;
#pragma unroll
    for (int q2 = 0; q2 < 4; ++q2) {
        uint4 st; st.x = pk[4*q2]; st.y = pk[4*q2+1]; st.z = pk[4*q2+2]; st.w = pk[4*q2+3];
        *(uint4*)(dst + q2 * 16) = st;
    }
}

__global__ __launch_bounds__(64)
void pack_w_kernel(const float* __restrict__ wa, const float* __restrict__ wb,
                   int8_t* __restrict__ B1, int8_t* __restrict__ B2) {
    const int kstep = blockIdx.x;   // 0..35
    const int nfrag = blockIdx.y;   // 0..15
    const float* wsrc = blockIdx.z ? wb : wa;
    int8_t* dst       = blockIdx.z ? B2 : B1;
    const int lane = threadIdx.x, quad = lane >> 4, l16 = lane & 15;
    const int co = nfrag * 16 + l16;
    uint32_t pk[4];
#pragma unroll
    for (int d = 0; d < 4; ++d) {
        uint32_t u = 0;
#pragma unroll
        for (int bb = 0; bb < 4; ++bb) {
            int k = kstep * 64 + quad * 16 + d * 4 + bb;
            int tap = k >> 8, ci = k & 255;
            float v = wsrc[((size_t)co * C + ci) * 9 + tap];
            uint32_t t = (v < 0.0f) ? 0xFFu : ((v != 0.0f) ? 1u : 0u);
            u |= t << (8 * bb);
        }
        pk[d] = u;
    }
    uint4 st; st.x = pk[0]; st.y = pk[1]; st.z = pk[2]; st.w = pk[3];
    *(uint4*)(dst + ((size_t)(nfrag * 36 + kstep) * 64 + lane) * 16) = st;
}

// Zero only the halos of both padded activation buffers (re-poisoned per run).
__global__ __launch_bounds__(256)
void halo_zero_kernel(int8_t* __restrict__ Aq, int8_t* __restrict__ Bq) {
    const int n = blockIdx.x;
    int8_t* buf = blockIdx.y ? Bq : Aq;
    const v4i z = (v4i){0, 0, 0, 0};
    // 228 halo pixels per n-slice: rows 0 & 57 (58 each), cols 0 & 57 (56 each)
    for (int idx = threadIdx.x; idx < 228 * 16; idx += 256) {
        int px = idx >> 4, c16 = idx & 15;
        int row, col;
        if (px < 58)       { row = 0;  col = px; }
        else if (px < 116) { row = 57; col = px - 58; }
        else { int i = px - 116; row = 1 + (i >> 1); col = (i & 1) * 57; }
        *(v4i*)(buf + (((size_t)n * HP + row) * HP + col) * C + c16 * 16) = z;
    }
}

template <int STAGE, int NF, int F0>
__device__ __forceinline__ void mconv_body(
    int8_t* lds, const int8_t* __restrict__ gA, const int8_t* __restrict__ Bpk,
    const float* __restrict__ gamma, const float* __restrict__ beta,
    const float* __restrict__ mean,  const float* __restrict__ var,
    const float* __restrict__ resid,
    int8_t* __restrict__ Bout, float* __restrict__ out,
    int n, int h2, int nb, int tid)
{
    const int lane = tid & 63, quad = lane >> 4, l16 = lane & 15;
    const int ng = (tid >> 6) & 1;

    // per-lane LDS A bases: group1 (tap rows 0,1): slot = hl + tr;
    // group2 (tap row 2): rows d=2(slot2), d=3(slot0) -> slot = 2-2*hl.
    int a1b[NF], a2b[NF];
#pragma unroll
    for (int f = 0; f < NF; ++f) {
        int mm = (F0 + f) * 16 + l16;
        int hl = (mm >= 56) ? 1 : 0;
        int w  = mm - 56 * hl;
        a1b[f] = hl * SLOT + w * PPIX + quad * 16;
        a2b[f] = (2 - 2 * hl) * SLOT + w * PPIX + quad * 16;
    }

    const v4i* bp[4];
#pragma unroll
    for (int nf = 0; nf < 4; ++nf)
        bp[nf] = (const v4i*)Bpk + ((size_t)((nb * 8 + ng * 4 + nf) * 36) * 64 + lane);

    v4i acc[NF][4];
#pragma unroll
    for (int f = 0; f < NF; ++f)
#pragma unroll
        for (int nf = 0; nf < 4; ++nf) acc[f][nf] = (v4i){0, 0, 0, 0};

    // ---- group 1: taps 0..5 (tap rows 0,1) ----
#pragma unroll 1
    for (int t = 0; t < 6; ++t) {
        const int tr = (t >= 3) ? 1 : 0;
        const int tc = t - 3 * tr;
        const int au = tr * SLOT + tc * PPIX;
#pragma unroll
        for (int cich = 0; cich < 4; ++cich) {
            v4i bfr[4];
#pragma unroll
            for (int nf = 0; nf < 4; ++nf)
                bfr[nf] = bp[nf][(t * 4 + cich) * 64];
            v4i afr[NF];
#pragma unroll
            for (int f = 0; f < NF; ++f)
                afr[f] = *(const v4i*)(lds + a1b[f] + au + cich * 64);
#pragma unroll
            for (int f = 0; f < NF; ++f)
#pragma unroll
                for (int nf = 0; nf < 4; ++nf)
                    acc[f][nf] = __builtin_amdgcn_mfma_i32_16x16x64_i8(
                        afr[f], bfr[nf], acc[f][nf], 0, 0, 0);
        }
    }

    // ---- ring reload: input row d=3 -> slot 0 ----
    __syncthreads();
    for (int idx = tid; idx < HP * 16; idx += 256) {
        int pix = idx >> 4, c16 = idx & 15;
        *(v4i*)(lds + pix * PPIX + c16 * 16) =
            *(const v4i*)(gA + ((size_t)(3 * HP + pix)) * C + c16 * 16);
    }
    __syncthreads();

    // ---- group 2: taps 6..8 (tap row 2) ----
#pragma unroll 1
    for (int t = 0; t < 3; ++t) {
        const int au = t * PPIX;
#pragma unroll
        for (int cich = 0; cich < 4; ++cich) {
            v4i bfr[4];
#pragma unroll
            for (int nf = 0; nf < 4; ++nf)
                bfr[nf] = bp[nf][((6 + t) * 4 + cich) * 64];
            v4i afr[NF];
#pragma unroll
            for (int f = 0; f < NF; ++f)
                afr[f] = *(const v4i*)(lds + a2b[f] + au + cich * 64);
#pragma unroll
            for (int f = 0; f < NF; ++f)
#pragma unroll
                for (int nf = 0; nf < 4; ++nf)
                    acc[f][nf] = __builtin_amdgcn_mfma_i32_16x16x64_i8(
                        afr[f], bfr[nf], acc[f][nf], 0, 0, 0);
        }
    }

    // ---- epilogue ----
    if (STAGE == 1) {
        __syncthreads();   // all slots now dead; reuse LDS as transpose buffer
#pragma unroll
        for (int nf = 0; nf < 4; ++nf) {
            const int co = (nb * 8 + ng * 4 + nf) * 16 + l16;
            double scd = (double)gamma[co] / sqrt((double)var[co] + 1e-5);
            float scale = (float)scd;
            float shift = (float)((double)beta[co] - (double)mean[co] * scd);
            const int col = ng * 64 + nf * 16 + l16;
#pragma unroll
            for (int f = 0; f < NF; ++f) {
#pragma unroll
                for (int reg = 0; reg < 4; ++reg) {
                    int mm = (F0 + f) * 16 + quad * 4 + reg;
                    float v = __fadd_rn(__fmul_rn((float)acc[f][nf][reg], scale), shift);
                    int8_t t8 = (v < 0.0f) ? (int8_t)-1
                              : ((v != 0.0f) ? (int8_t)1 : (int8_t)0);
                    lds[mm * OST + col] = t8;
                }
            }
        }
        __syncthreads();
        // coalesced copy-out: 112 px x 128 co (this nb half)
        for (int idx = tid; idx < 112 * 8; idx += 256) {
            int mm = idx >> 3, c = idx & 7;
            int hl = (mm >= 56) ? 1 : 0;
            int ww = mm - 56 * hl;
            int oh = h2 * 2 + hl;
            *(v4i*)(Bout + (((size_t)n * HP + oh + 1) * HP + ww + 1) * C + nb * 128 + c * 16)
                = *(const v4i*)(lds + mm * OST + c * 16);
        }
    } else {
#pragma unroll
        for (int nf = 0; nf < 4; ++nf) {
            const int co = (nb * 8 + ng * 4 + nf) * 16 + l16;
            double scd = (double)gamma[co] / sqrt((double)var[co] + 1e-5);
            float scale = (float)scd;
            float shift = (float)((double)beta[co] - (double)mean[co] * scd);
#pragma unroll
            for (int f = 0; f < NF; ++f) {
                int mmb = (F0 + f) * 16 + quad * 4;   // 4-aligned: hl uniform over reg
                int hl = (mmb >= 56) ? 1 : 0;
                int w0 = mmb - 56 * hl;
                int oh = h2 * 2 + hl;
                size_t ridx = (((size_t)n * C + co) * H + oh) * W + w0;
                float4 rv = *(const float4*)(resid + ridx);
                float rr[4] = {rv.x, rv.y, rv.z, rv.w};
                float oo[4];
#pragma unroll
                for (int reg = 0; reg < 4; ++reg) {
                    float v = __fadd_rn(__fmul_rn((float)acc[f][nf][reg], scale), shift);
                    float o = v + rr[reg];
                    oo[reg] = fminf(1.0f, fmaxf(-1.0f, o));
                }
                float4 ov; ov.x = oo[0]; ov.y = oo[1]; ov.z = oo[2]; ov.w = oo[3];
                *(float4*)(out + ridx) = ov;
            }
        }
    }
}

template <int STAGE>
__global__ __launch_bounds__(256, 3)
void mconv_kernel(const int8_t* __restrict__ Aq, const int8_t* __restrict__ Bpk,
                  const float* __restrict__ gamma, const float* __restrict__ beta,
                  const float* __restrict__ mean,  const float* __restrict__ var,
                  const float* __restrict__ resid,
                  int8_t* __restrict__ Bout, float* __restrict__ out) {
    const int h2 = blockIdx.x, n = blockIdx.y, nb = blockIdx.z;
    const int tid = threadIdx.x;
    __shared__ int8_t lds[3 * SLOT];   // 47328 B

    const int8_t* gA = Aq + ((size_t)n * HP + h2 * 2) * HP * C;
    // stage input rows d=0..2 into slots 0..2
    for (int idx = tid; idx < 3 * HP * 16; idx += 256) {
        int d = idx / (HP * 16);
        int pix = (idx % (HP * 16)) >> 4, c16 = idx & 15;
        *(v4i*)(lds + d * SLOT + pix * PPIX + c16 * 16) =
            *(const v4i*)(gA + ((size_t)(d * HP + pix)) * C + c16 * 16);
    }
    __syncthreads();

    if ((tid >> 7) == 0)
        mconv_body<STAGE, 4, 0>(lds, gA, Bpk, gamma, beta, mean, var, resid,
                                Bout, out, n, h2, nb, tid);
    else
        mconv_body<STAGE, 3, 4>(lds, gA, Bpk, gamma, beta, mean, var, resid,
                                Bout, out, n, h2, nb, tid);
}

extern "C" void kernel_launch(void* const* d_in, const int* in_sizes, int n_in,
                              void* d_out, int out_size, void* d_ws, size_t ws_size,
                              hipStream_t stream) {
    const float* x  = (const float*)d_in[0];
    const float* w1 = (const float*)d_in[1];
    const float* g1 = (const float*)d_in[2];
    const float* b1 = (const float*)d_in[3];
    const float* m1 = (const float*)d_in[4];
    const float* v1 = (const float*)d_in[5];
    const float* w2 = (const float*)d_in[6];
    const float* g2 = (const float*)d_in[7];
    const float* b2 = (const float*)d_in[8];
    const float* m2 = (const float*)d_in[9];
    const float* v2 = (const float*)d_in[10];
    float* out = (float*)d_out;

    uint8_t* ws = (uint8_t*)d_ws;
    const size_t ASZ = (size_t)NB * HP * HP * C;       // 55,083,008 B per act buffer
    const size_t WPK = (size_t)16 * 36 * 64 * 16;      // 589,824 B per packed weight
    int8_t* Aq   = (int8_t*)(ws);
    int8_t* Bq   = (int8_t*)(ws + ASZ);
    int8_t* Bpk1 = (int8_t*)(ws + 2 * ASZ);
    int8_t* Bpk2 = (int8_t*)(ws + 2 * ASZ + WPK);

    halo_zero_kernel<<<dim3(NB, 2), 256, 0, stream>>>(Aq, Bq);
    pack_w_kernel<<<dim3(36, 16, 2), 64, 0, stream>>>(w1, w2, Bpk1, Bpk2);
    pack_x_kernel<<<dim3(H, NB), 256, 0, stream>>>(x, Aq);
    mconv_kernel<1><<<dim3(28, NB, 2), 256, 0, stream>>>(Aq, Bpk1, g1, b1, m1, v1,
                                                         nullptr, Bq, nullptr);
    mconv_kernel<2><<<dim3(28, NB, 2), 256, 0, stream>>>(Bq, Bpk2, g2, b2, m2, v2,
                                                         x, nullptr, out);
}

// Round 5
// 646.143 us; speedup vs baseline: 1.0790x; 1.0790x over previous
//
#include <hip/hip_runtime.h>
#include <stdint.h>

// ---------------------------------------------------------------------------
// Ternary 3x3 conv block via i8 MFMA implicit GEMM, latency-pipelined.
//
// Activations: NHWC i8 ternary {-1,0,+1}, padded [64][58][58][256], halo = 0.
// Weights pre-packed in MFMA B-fragment order:
//   Bpk[nfrag(16)][unit(36)][lane(64)][16B], unit = tap*4 + cich (k-chunk),
//   flat-contiguous in unit -> B prefetch pointer strides 1024 B.
// mconv block: M=112 (2 out rows) x N=256 x K=2304, 4 waves (N-split 64 each).
//   4 input rows staged once in LDS (63.1 KB, PPIX=272 pad: 2-way-free banks).
//   K-loop: per unit, prefetch next B (global, dbuf) -> 7 ds_read_b128 A ->
//   28 MFMA (v_mfma_i32_16x16x64_i8). C/D: col=lane&15, row=(lane>>4)*4+reg.
// ---------------------------------------------------------------------------

#define NB 64
#define C  256
#define H  56
#define W  56
#define HP 58
#define PPIX 272                 // padded bytes per pixel in LDS (17*16)
#define SLOT (HP * PPIX)         // bytes per LDS row slot
#define OST 272                  // stage-1 transpose row stride (256+16)

typedef int v4i __attribute__((ext_vector_type(4)));

// ---------------- pack input: NCHW fp32 -> padded NHWC ternary i8 ----------
__global__ __launch_bounds__(256)
void pack_x_kernel(const float* __restrict__ x, int8_t* __restrict__ Aq) {
    const int h = blockIdx.x, n = blockIdx.y;
    const int w  = threadIdx.x & 63;   // 0..55 valid
    const int cq = threadIdx.x >> 6;   // 64-channel group

    __shared__ int8_t st[56 * OST];    // [w][c] ternary bytes, padded stride

    const float* xp = x + (((size_t)n * C + cq * 64) * H + h) * W + w;
#pragma unroll
    for (int i = 0; i < 16; ++i) {     // 4 channels per iter -> one u32 store
        uint32_t u = 0;
#pragma unroll
        for (int b = 0; b < 4; ++b) {
            float v = (w < 56) ? xp[(size_t)(i * 4 + b) * (H * W)] : 0.0f;
            uint32_t t = (v < 0.0f) ? 0xFFu : ((v != 0.0f) ? 1u : 0u);
            u |= t << (8 * b);
        }
        if (w < 56)
            *(uint32_t*)(st + w * OST + cq * 64 + i * 4) = u;
    }
    __syncthreads();
    // coalesced out: 56 pixels x 256 B contiguous at (h+1, 1)
    int8_t* dst = Aq + (((size_t)n * HP + h + 1) * HP + 1) * C;
    for (int idx = threadIdx.x; idx < 56 * 16; idx += 256) {
        int pix = idx >> 4, c16 = idx & 15;
        *(v4i*)(dst + (size_t)pix * C + c16 * 16) =
            *(const v4i*)(st + pix * OST + c16 * 16);
    }
}

// ---------------- pack weights into B-fragment order -----------------------
__global__ __launch_bounds__(64)
void pack_w_kernel(const float* __restrict__ wa, const float* __restrict__ wb,
                   int8_t* __restrict__ B1, int8_t* __restrict__ B2) {
    const int kstep = blockIdx.x;   // 0..35 (= tap*4 + cich)
    const int nfrag = blockIdx.y;   // 0..15
    const float* wsrc = blockIdx.z ? wb : wa;
    int8_t* dst       = blockIdx.z ? B2 : B1;
    const int lane = threadIdx.x, quad = lane >> 4, l16 = lane & 15;
    const int co = nfrag * 16 + l16;
    uint32_t pk[4];
#pragma unroll
    for (int d = 0; d < 4; ++d) {
        uint32_t u = 0;
#pragma unroll
        for (int bb = 0; bb < 4; ++bb) {
            int k = kstep * 64 + quad * 16 + d * 4 + bb;
            int tap = k >> 8, ci = k & 255;
            float v = wsrc[((size_t)co * C + ci) * 9 + tap];
            uint32_t t = (v < 0.0f) ? 0xFFu : ((v != 0.0f) ? 1u : 0u);
            u |= t << (8 * bb);
        }
        pk[d] = u;
    }
    uint4 st; st.x = pk[0]; st.y = pk[1]; st.z = pk[2]; st.w = pk[3];
    *(uint4*)(dst + ((size_t)(nfrag * 36 + kstep) * 64 + lane) * 16) = st;
}

// ---------------- zero halos of both padded activation buffers -------------
__global__ __launch_bounds__(256)
void halo_zero_kernel(int8_t* __restrict__ Aq, int8_t* __restrict__ Bq) {
    const int n = blockIdx.x;
    int8_t* buf = blockIdx.y ? Bq : Aq;
    const v4i z = (v4i){0, 0, 0, 0};
    for (int idx = threadIdx.x; idx < 228 * 16; idx += 256) {
        int px = idx >> 4, c16 = idx & 15;
        int row, col;
        if (px < 58)       { row = 0;  col = px; }
        else if (px < 116) { row = 57; col = px - 58; }
        else { int i = px - 116; row = 1 + (i >> 1); col = (i & 1) * 57; }
        *(v4i*)(buf + (((size_t)n * HP + row) * HP + col) * C + c16 * 16) = z;
    }
}

// ---------------- BN constants (match prior absmax-0 double path) ----------
__global__ __launch_bounds__(256)
void bn_prep_kernel(const float* g1, const float* b1, const float* m1, const float* v1,
                    const float* g2, const float* b2, const float* m2, const float* v2,
                    float* __restrict__ sc, float* __restrict__ sh) {
    const int co = threadIdx.x;
    const float* g = blockIdx.x ? g2 : g1;
    const float* b = blockIdx.x ? b2 : b1;
    const float* m = blockIdx.x ? m2 : m1;
    const float* v = blockIdx.x ? v2 : v1;
    double scd = (double)g[co] / sqrt((double)v[co] + 1e-5);
    sc[blockIdx.x * C + co] = (float)scd;
    sh[blockIdx.x * C + co] = (float)((double)b[co] - (double)m[co] * scd);
}

// ---------------- the conv kernels -----------------------------------------
// STAGE 1: GEMM -> BN -> ternarize -> LDS transpose -> coalesced NHWC i8.
// STAGE 2: GEMM -> BN -> +residual -> clip -> fp32 NCHW (float4).
template <int STAGE>
__global__ __launch_bounds__(256, 2)
void mconv_kernel(const int8_t* __restrict__ Aq, const int8_t* __restrict__ Bpk,
                  const float* __restrict__ scp, const float* __restrict__ shp,
                  const float* __restrict__ resid,
                  int8_t* __restrict__ Bout, float* __restrict__ out) {
    const int h2 = blockIdx.x;   // output rows h2*2, h2*2+1
    const int n  = blockIdx.y;
    const int tid = threadIdx.x;
    const int wv = tid >> 6, lane = tid & 63, quad = lane >> 4, l16 = lane & 15;

    __shared__ int8_t lds[4 * SLOT];   // 63104 B

    // stage input rows h2*2 .. h2*2+3 (row d -> d*SLOT, pixel stride PPIX)
    const int8_t* gA = Aq + ((size_t)n * HP + h2 * 2) * HP * C;
    for (int idx = tid; idx < 4 * HP * 16; idx += 256) {
        int pix = idx >> 4, c16 = idx & 15;        // pix = d*HP + col
        *(v4i*)(lds + pix * PPIX + c16 * 16) =
            *(const v4i*)(gA + (size_t)pix * C + c16 * 16);
    }
    __syncthreads();

    // per-lane A bases: m = f*16 + l16 -> (hl, w)
    int abase[7];
#pragma unroll
    for (int f = 0; f < 7; ++f) {
        int mm = f * 16 + l16;
        int hl = (mm >= 56) ? 1 : 0;
        int w  = mm - 56 * hl;
        abase[f] = hl * SLOT + w * PPIX + quad * 16;
    }

    // B fragment pointers: wave wv owns nfrags wv*4 .. wv*4+3
    const int8_t* bq[4];
#pragma unroll
    for (int nf = 0; nf < 4; ++nf)
        bq[nf] = Bpk + (size_t)((wv * 4 + nf) * 36) * 1024 + lane * 16;

    v4i bcur[4];
#pragma unroll
    for (int nf = 0; nf < 4; ++nf) bcur[nf] = *(const v4i*)(bq[nf]);

    v4i acc[7][4];
#pragma unroll
    for (int f = 0; f < 7; ++f)
#pragma unroll
        for (int nf = 0; nf < 4; ++nf) acc[f][nf] = (v4i){0, 0, 0, 0};

#pragma unroll 1
    for (int t = 0; t < 9; ++t) {
        const int r = (t >= 6) ? 2 : ((t >= 3) ? 1 : 0);
        const int c = t - 3 * r;
        const int au = r * SLOT + c * PPIX;
#pragma unroll
        for (int ci = 0; ci < 4; ++ci) {
            // prefetch next unit's B fragments (flat-contiguous; final
            // iteration reads 1KB past Bpk's tail -> still inside d_ws)
            v4i bnxt[4];
#pragma unroll
            for (int nf = 0; nf < 4; ++nf)
                bnxt[nf] = *(const v4i*)(bq[nf] + (ci + 1) * 1024);
            v4i afr[7];
#pragma unroll
            for (int f = 0; f < 7; ++f)
                afr[f] = *(const v4i*)(lds + abase[f] + au + ci * 64);
#pragma unroll
            for (int f = 0; f < 7; ++f)
#pragma unroll
                for (int nf = 0; nf < 4; ++nf)
                    acc[f][nf] = __builtin_amdgcn_mfma_i32_16x16x64_i8(
                        afr[f], bcur[nf], acc[f][nf], 0, 0, 0);
#pragma unroll
            for (int nf = 0; nf < 4; ++nf) bcur[nf] = bnxt[nf];
        }
#pragma unroll
        for (int nf = 0; nf < 4; ++nf) bq[nf] += 4096;
    }

    // ---- epilogue ----
    if (STAGE == 1) {
        __syncthreads();   // K-loop LDS dead; reuse as transpose buffer
#pragma unroll
        for (int nf = 0; nf < 4; ++nf) {
            const int co = (wv * 4 + nf) * 16 + l16;
            const float scale = scp[co], shift = shp[co];
#pragma unroll
            for (int f = 0; f < 7; ++f) {
#pragma unroll
                for (int reg = 0; reg < 4; ++reg) {
                    int mm = f * 16 + quad * 4 + reg;
                    float v = __fadd_rn(__fmul_rn((float)acc[f][nf][reg], scale), shift);
                    int8_t t8 = (v < 0.0f) ? (int8_t)-1
                              : ((v != 0.0f) ? (int8_t)1 : (int8_t)0);
                    lds[mm * OST + co] = t8;
                }
            }
        }
        __syncthreads();
        // coalesced out: 112 pixels x 256 B
        for (int idx = tid; idx < 112 * 16; idx += 256) {
            int mm = idx >> 4, c16 = idx & 15;
            int hl = (mm >= 56) ? 1 : 0;
            int ww = mm - 56 * hl;
            int oh = h2 * 2 + hl;
            *(v4i*)(Bout + (((size_t)n * HP + oh + 1) * HP + ww + 1) * C + c16 * 16)
                = *(const v4i*)(lds + mm * OST + c16 * 16);
        }
    } else {
#pragma unroll
        for (int nf = 0; nf < 4; ++nf) {
            const int co = (wv * 4 + nf) * 16 + l16;
            const float scale = scp[co], shift = shp[co];
#pragma unroll
            for (int f = 0; f < 7; ++f) {
                int mmb = f * 16 + quad * 4;   // 4-aligned: row uniform over reg
                int hl = (mmb >= 56) ? 1 : 0;
                int w0 = mmb - 56 * hl;
                int oh = h2 * 2 + hl;
                size_t ridx = (((size_t)n * C + co) * H + oh) * W + w0;
                float4 rv = *(const float4*)(resid + ridx);
                float rr[4] = {rv.x, rv.y, rv.z, rv.w};
                float oo[4];
#pragma unroll
                for (int reg = 0; reg < 4; ++reg) {
                    float v = __fadd_rn(__fmul_rn((float)acc[f][nf][reg], scale), shift);
                    float o = v + rr[reg];
                    oo[reg] = fminf(1.0f, fmaxf(-1.0f, o));
                }
                float4 ov; ov.x = oo[0]; ov.y = oo[1]; ov.z = oo[2]; ov.w = oo[3];
                *(float4*)(out + ridx) = ov;
            }
        }
    }
}

extern "C" void kernel_launch(void* const* d_in, const int* in_sizes, int n_in,
                              void* d_out, int out_size, void* d_ws, size_t ws_size,
                              hipStream_t stream) {
    const float* x  = (const float*)d_in[0];
    const float* w1 = (const float*)d_in[1];
    const float* g1 = (const float*)d_in[2];
    const float* b1 = (const float*)d_in[3];
    const float* m1 = (const float*)d_in[4];
    const float* v1 = (const float*)d_in[5];
    const float* w2 = (const float*)d_in[6];
    const float* g2 = (const float*)d_in[7];
    const float* b2 = (const float*)d_in[8];
    const float* m2 = (const float*)d_in[9];
    const float* v2 = (const float*)d_in[10];
    float* out = (float*)d_out;

    uint8_t* ws = (uint8_t*)d_ws;
    const size_t ASZ = (size_t)NB * HP * HP * C;       // 55,083,008 B per act buffer
    const size_t WPK = (size_t)16 * 36 * 64 * 16;      // 589,824 B per packed weight
    int8_t* Aq   = (int8_t*)(ws);
    int8_t* Bq   = (int8_t*)(ws + ASZ);
    int8_t* Bpk1 = (int8_t*)(ws + 2 * ASZ);
    int8_t* Bpk2 = (int8_t*)(ws + 2 * ASZ + WPK);
    float*  scb  = (float*)(ws + 2 * ASZ + 2 * WPK);           // [2][256]
    float*  shb  = (float*)(ws + 2 * ASZ + 2 * WPK + 2048);    // [2][256]

    halo_zero_kernel<<<dim3(NB, 2), 256, 0, stream>>>(Aq, Bq);
    bn_prep_kernel<<<dim3(2), 256, 0, stream>>>(g1, b1, m1, v1, g2, b2, m2, v2,
                                                scb, shb);
    pack_w_kernel<<<dim3(36, 16, 2), 64, 0, stream>>>(w1, w2, Bpk1, Bpk2);
    pack_x_kernel<<<dim3(H, NB), 256, 0, stream>>>(x, Aq);
    mconv_kernel<1><<<dim3(28, NB), 256, 0, stream>>>(Aq, Bpk1, scb, shb,
                                                      nullptr, Bq, nullptr);
    mconv_kernel<2><<<dim3(28, NB), 256, 0, stream>>>(Bq, Bpk2, scb + C, shb + C,
                                                      x, nullptr, out);
}